// Round 13
// baseline (361.432 us; speedup 1.0000x reference)
//
#include <hip/hip_runtime.h>

#define N_NODES 200000
#define N_EDGES 6400000
#define N_GRAPHS 2000

// level-1: megabuckets of 2048 dst nodes
#define MBSHIFT 11
#define NMB 98             // ceil(200000/2048)
#define MBCAP 67584        // mean 65536 + 8 sigma
#define CHUNKA 4096        // edges per partA block
#define PBLKA 1563         // ceil(6.4M/4096)
#define CHUNKB 8192        // edges per partB chunk
#define PB 9               // partB blocks per megabucket (9*8192 >= MBCAP)

// level-2: fine buckets of 128 dst nodes
#define FSHIFT 7
#define NBUCK 1563         // ceil(200000/128)
#define CAPF 4608          // mean 4096 + 8 sigma

typedef __attribute__((ext_vector_type(4))) int   i32x4;
typedef __attribute__((ext_vector_type(4))) float f32x4;
typedef __attribute__((ext_vector_type(2))) float f32x2;

// ---- bf16 helpers (storage = packed u16 pairs in uint; compute = f32) ----
__device__ __forceinline__ float bf_lo(unsigned v) { return __uint_as_float(v << 16); }
__device__ __forceinline__ float bf_hi(unsigned v) { return __uint_as_float(v & 0xFFFF0000u); }
__device__ __forceinline__ unsigned pack_bf2(float lo, float hi) {
  unsigned a = __float_as_uint(lo), b = __float_as_uint(hi);
  a = (a + 0x7FFFu + ((a >> 16) & 1u)) >> 16;
  b = (b + 0x7FFFu + ((b >> 16) & 1u)) >> 16;
  return a | (b << 16);
}

__global__ __launch_bounds__(256) void init_cursors(int* __restrict__ gcurA,
                                                    int* __restrict__ gcur2) {
  int i = blockIdx.x * 256 + threadIdx.x;
  if (i < NMB) gcurA[i] = i * MBCAP;
  if (i < NMB * 16) gcur2[i] = i * CAPF;
}

// pass A: single nt-int4 read of src/dst into registers -> LDS counting sort ->
// parallel binary-search copy-out (contiguous per-bin runs).
__global__ __launch_bounds__(256) void partA(
    const int* __restrict__ src, const int* __restrict__ dst,
    int* __restrict__ gcurA, int* __restrict__ colA) {
  __shared__ int hist[NMB], base[NMB], lcur[NMB];
  __shared__ int sc[128];
  __shared__ int sorted[CHUNKA];  // 16 KB
  int t = threadIdx.x;
  for (int i = t; i < NMB; i += 256) hist[i] = 0;
  __syncthreads();
  int e0 = blockIdx.x * CHUNKA;
  int cnt = N_EDGES - e0; if (cnt > CHUNKA) cnt = CHUNKA;  // 4096 or 2048 (mult of 1024)
  int pr[16], br[16];
#pragma unroll
  for (int k = 0; k < 4; k++) {
    if (k * 1024 < cnt) {
      int i = e0 + k * 1024 + t * 4;
      i32x4 d4 = __builtin_nontemporal_load(reinterpret_cast<const i32x4*>(dst + i));
      i32x4 s4 = __builtin_nontemporal_load(reinterpret_cast<const i32x4*>(src + i));
      br[4*k+0] = d4.x >> MBSHIFT; pr[4*k+0] = (s4.x << MBSHIFT) | (d4.x & 2047);
      br[4*k+1] = d4.y >> MBSHIFT; pr[4*k+1] = (s4.y << MBSHIFT) | (d4.y & 2047);
      br[4*k+2] = d4.z >> MBSHIFT; pr[4*k+2] = (s4.z << MBSHIFT) | (d4.z & 2047);
      br[4*k+3] = d4.w >> MBSHIFT; pr[4*k+3] = (s4.w << MBSHIFT) | (d4.w & 2047);
      atomicAdd(&hist[br[4*k+0]], 1); atomicAdd(&hist[br[4*k+1]], 1);
      atomicAdd(&hist[br[4*k+2]], 1); atomicAdd(&hist[br[4*k+3]], 1);
    } else {
      br[4*k+0] = -1; br[4*k+1] = -1; br[4*k+2] = -1; br[4*k+3] = -1;
      pr[4*k+0] = 0;  pr[4*k+1] = 0;  pr[4*k+2] = 0;  pr[4*k+3] = 0;
    }
  }
  __syncthreads();
  if (t < 128) sc[t] = (t < NMB) ? hist[t] : 0;
  __syncthreads();
  for (int off = 1; off < 128; off <<= 1) {
    int v = (t < 128 && t >= off) ? sc[t - off] : 0;
    __syncthreads();
    if (t < 128) sc[t] += v;
    __syncthreads();
  }
  if (t < NMB) {
    lcur[t] = sc[t] - hist[t];
    base[t] = hist[t] ? atomicAdd(&gcurA[t], hist[t]) : 0;
  }
  __syncthreads();
#pragma unroll
  for (int k = 0; k < 16; k++) {
    int b = br[k];
    if (b >= 0) {
      int r = atomicAdd(&lcur[b], 1);
      sorted[r] = pr[k];
    }
  }
  __syncthreads();
  // parallel copy-out: bin of element i = first b with sc[b] > i (7-step search)
  for (int i = t; i < cnt; i += 256) {
    int lo = 0, hi = NMB;
    while (lo < hi) { int mid = (lo + hi) >> 1; if (sc[mid] <= i) lo = mid + 1; else hi = mid; }
    int b = lo;
    int pos = base[b] + (i - (sc[b] - hist[b]));
    if (pos < (b + 1) * MBCAP) colA[pos] = sorted[i];  // 8-sigma guard
  }
}

// pass B: single nt-int4 read into 32 regs/thread -> direct global scatter into
// the block's reserved (contiguous, block-private) per-fine-bucket ranges.
__global__ __launch_bounds__(256) void partB(
    const int* __restrict__ gcurA, const int* __restrict__ colA,
    int* __restrict__ gcur2, int* __restrict__ col) {
  __shared__ int hist[16], base[16], lcur[16];
  int t = threadIdx.x;
  int mb = blockIdx.x / PB, j = blockIdx.x % PB;
  int mbbase = mb * MBCAP;
  int mbcnt = gcurA[mb] - mbbase; if (mbcnt > MBCAP) mbcnt = MBCAP;
  int c0 = j * CHUNKB;
  int cnt = mbcnt - c0;
  if (cnt > CHUNKB) cnt = CHUNKB;
  if (cnt < 0) cnt = 0;
  if (t < 16) { hist[t] = 0; }
  __syncthreads();
  const int* seg = colA + mbbase + c0;
  int pr[32];
#pragma unroll
  for (int k = 0; k < 8; k++) {
    int i = k * 1024 + t * 4;
    if (i + 3 < cnt) {
      i32x4 v = __builtin_nontemporal_load(reinterpret_cast<const i32x4*>(seg + i));
      pr[4*k+0] = v.x; pr[4*k+1] = v.y; pr[4*k+2] = v.z; pr[4*k+3] = v.w;
      atomicAdd(&hist[(v.x & 2047) >> FSHIFT], 1);
      atomicAdd(&hist[(v.y & 2047) >> FSHIFT], 1);
      atomicAdd(&hist[(v.z & 2047) >> FSHIFT], 1);
      atomicAdd(&hist[(v.w & 2047) >> FSHIFT], 1);
    } else {
#pragma unroll
      for (int q = 0; q < 4; q++) {
        int i2 = i + q;
        if (i2 < cnt) {
          int p = seg[i2];
          pr[4*k+q] = p;
          atomicAdd(&hist[(p & 2047) >> FSHIFT], 1);
        } else pr[4*k+q] = -1;
      }
    }
  }
  __syncthreads();
  if (t < 16) {
    base[t] = hist[t] ? atomicAdd(&gcur2[mb * 16 + t], hist[t]) : 0;
    lcur[t] = 0;
  }
  __syncthreads();
#pragma unroll
  for (int k = 0; k < 32; k++) {
    int p = pr[k];
    if (p >= 0) {
      int b = (p & 2047) >> FSHIFT;
      int r = atomicAdd(&lcur[b], 1);
      int pos = base[b] + r;
      if (pos < (mb * 16 + b + 1) * CAPF)                  // 8-sigma guard
        col[pos] = ((p >> MBSHIFT) << FSHIFT) | (p & 127); // src<<7 | dst&127
    }
  }
}

// fine sort: single nt read into 18 regs/thread -> 128-bin LDS sort -> nt linear write-back
__global__ __launch_bounds__(256) void sort_fine(
    const int* __restrict__ gcur2, int* __restrict__ col,
    int* __restrict__ rowstart, int* __restrict__ rowcnt) {
  __shared__ int hist[128], sc[128], lcur[128];
  __shared__ int sorted[CAPF];   // 18 KB
  int t = threadIdx.x;
  int fb = blockIdx.x;
  int beg = fb * CAPF;
  int cnt = gcur2[fb] - beg; if (cnt > CAPF) cnt = CAPF;
  if (t < 128) hist[t] = 0;
  __syncthreads();
  int pr[18];
#pragma unroll
  for (int k = 0; k < 18; k++) {
    int i = k * 256 + t;
    int p = (i < cnt) ? __builtin_nontemporal_load(col + beg + i) : -1;
    pr[k] = p;
    if (p >= 0) atomicAdd(&hist[p & 127], 1);
  }
  __syncthreads();
  if (t < 128) sc[t] = hist[t];
  __syncthreads();
  for (int off = 1; off < 128; off <<= 1) {
    int v = (t < 128 && t >= off) ? sc[t - off] : 0;
    __syncthreads();
    if (t < 128) sc[t] += v;
    __syncthreads();
  }
  if (t < 128) {
    int excl = sc[t] - hist[t];
    lcur[t] = excl;
    int n = fb * 128 + t;
    if (n < N_NODES) { rowstart[n] = beg + excl; rowcnt[n] = hist[t]; }
  }
  __syncthreads();
#pragma unroll
  for (int k = 0; k < 18; k++) {
    int p = pr[k];
    if (p >= 0) {
      int r = atomicAdd(&lcur[p & 127], 1);
      sorted[r] = p >> FSHIFT;   // src only, grouped by dst
    }
  }
  __syncthreads();
  for (int i = t; i < cnt; i += 256)
    __builtin_nontemporal_store(sorted[i], col + beg + i);
}

// ---------- layer 1 aggregation: 32 lanes per node (2 nodes/wave), dim 2 ----------
// col reads nt (stream, read-once); x reads cached (1.6 MB, should stay L2-hot).
__global__ __launch_bounds__(256) void aggr2_wave(
    const int* __restrict__ rowstart, const int* __restrict__ rowcnt,
    const int* __restrict__ col, const float* __restrict__ x,
    float* __restrict__ agg2) {
  int n = blockIdx.x * 8 + (threadIdx.x >> 5);  // 200000 = 25000*8 exactly
  int l32 = threadIdx.x & 31;
  int e0 = rowstart[n], c = rowcnt[n];
  float a0 = 0.f, a1 = 0.f;
  for (int idx = l32; idx < c; idx += 32) {
    int s = __builtin_nontemporal_load(col + e0 + idx);
    float2 u = *reinterpret_cast<const float2*>(x + 2 * s);
    a0 += u.x; a1 += u.y;
  }
#pragma unroll
  for (int off = 1; off <= 16; off <<= 1) {  // stays within each 32-lane group
    a0 += __shfl_xor(a0, off, 64);
    a1 += __shfl_xor(a1, off, 64);
  }
  if (l32 == 0) {
    f32x2 o = {a0, a1};
    __builtin_nontemporal_store(o, reinterpret_cast<f32x2*>(agg2 + 2 * n));
  }
}

// ---------- layers 2/3 aggregation: one wave per node, dim 16, bf16 gather ----------
// col reads nt; hbf gathers cached (6.4 MB, target of L2 residency); agg stores nt.
__global__ __launch_bounds__(256) void aggr16_wave(
    const int* __restrict__ rowstart, const int* __restrict__ rowcnt,
    const int* __restrict__ col, const uint4* __restrict__ hbf,
    float* __restrict__ agg) {
  int n = blockIdx.x * 4 + (threadIdx.x >> 6);
  int lane = threadIdx.x & 63;
  int e0 = rowstart[n], c = rowcnt[n];
  float a[8];
#pragma unroll
  for (int j = 0; j < 8; j++) a[j] = 0.f;
  int half = lane & 1;
  for (int idx = (lane >> 1); idx < c; idx += 32) {
    int s = __builtin_nontemporal_load(col + e0 + idx);
    uint4 u = hbf[2 * s + half];   // 8 bf16 = 16 B; pair covers the 32B row (one 64B line)
    a[0] += bf_lo(u.x); a[1] += bf_hi(u.x);
    a[2] += bf_lo(u.y); a[3] += bf_hi(u.y);
    a[4] += bf_lo(u.z); a[5] += bf_hi(u.z);
    a[6] += bf_lo(u.w); a[7] += bf_hi(u.w);
  }
#pragma unroll
  for (int off = 2; off <= 32; off <<= 1) {
#pragma unroll
    for (int j = 0; j < 8; j++) a[j] += __shfl_xor(a[j], off, 64);
  }
  if (lane < 2) {
    float* dstp = agg + (size_t)n * 16 + 8 * lane;
    f32x4 o0 = {a[0], a[1], a[2], a[3]};
    f32x4 o1 = {a[4], a[5], a[6], a[7]};
    __builtin_nontemporal_store(o0, reinterpret_cast<f32x4*>(dstp));
    __builtin_nontemporal_store(o1, reinterpret_cast<f32x4*>(dstp + 4));
  }
}

// ---------- layer 1 node MLP (2 -> 16 -> 16), outer relu, bf16 out ----------
__global__ __launch_bounds__(256) void node_l1(
    const float* __restrict__ x, const float* __restrict__ agg2,
    const float* __restrict__ Wa, const float* __restrict__ ba,
    const float* __restrict__ Wb, const float* __restrict__ bb,
    uint4* __restrict__ out) {
  __shared__ float sWa[32], sba[16], sWb[256], sbb[16];
  int t = threadIdx.x;
  if (t < 32) sWa[t] = Wa[t];
  if (t < 16) { sba[t] = ba[t]; sbb[t] = bb[t]; }
  for (int i = t; i < 256; i += 256) sWb[i] = Wb[i];
  __syncthreads();
  int n = blockIdx.x * blockDim.x + t;
  if (n >= N_NODES) return;
  float2 xv = *reinterpret_cast<const float2*>(x + 2 * n);
  float2 av = *reinterpret_cast<const float2*>(agg2 + 2 * n);
  float v0 = xv.x + av.x, v1 = xv.y + av.y;
  float h1[16];
#pragma unroll
  for (int j = 0; j < 16; j++)
    h1[j] = fmaxf(fmaf(v0, sWa[j], fmaf(v1, sWa[16 + j], sba[j])), 0.f);
  float o[16];
#pragma unroll
  for (int j = 0; j < 16; j++) {
    float s = sbb[j];
#pragma unroll
    for (int k = 0; k < 16; k++) s = fmaf(h1[k], sWb[k * 16 + j], s);
    o[j] = fmaxf(s, 0.f);
  }
  out[2 * n]     = make_uint4(pack_bf2(o[0], o[1]),  pack_bf2(o[2], o[3]),
                              pack_bf2(o[4], o[5]),  pack_bf2(o[6], o[7]));
  out[2 * n + 1] = make_uint4(pack_bf2(o[8], o[9]),  pack_bf2(o[10], o[11]),
                              pack_bf2(o[12], o[13]), pack_bf2(o[14], o[15]));
}

// ---------- layers 2/3 node MLP (16 -> 16 -> 16), outer relu, bf16 in/out ----------
__global__ __launch_bounds__(256) void node16(
    const uint4* __restrict__ hin, const float* __restrict__ aggr,
    const float* __restrict__ Wa, const float* __restrict__ ba,
    const float* __restrict__ Wb, const float* __restrict__ bb,
    uint4* __restrict__ out) {
  __shared__ float sWa[256], sba[16], sWb[256], sbb[16];
  int t = threadIdx.x;
  if (t < 16) { sba[t] = ba[t]; sbb[t] = bb[t]; }
  for (int i = t; i < 256; i += 256) { sWa[i] = Wa[i]; sWb[i] = Wb[i]; }
  __syncthreads();
  int n = blockIdx.x * blockDim.x + t;
  if (n >= N_NODES) return;
  uint4 r0 = hin[2 * n], r1 = hin[2 * n + 1];
  const float4* ap = reinterpret_cast<const float4*>(aggr + 16 * n);
  float4 a0 = ap[0], a1 = ap[1], a2 = ap[2], a3 = ap[3];
  float v[16];
  v[0]  = bf_lo(r0.x) + a0.x;  v[1]  = bf_hi(r0.x) + a0.y;
  v[2]  = bf_lo(r0.y) + a0.z;  v[3]  = bf_hi(r0.y) + a0.w;
  v[4]  = bf_lo(r0.z) + a1.x;  v[5]  = bf_hi(r0.z) + a1.y;
  v[6]  = bf_lo(r0.w) + a1.z;  v[7]  = bf_hi(r0.w) + a1.w;
  v[8]  = bf_lo(r1.x) + a2.x;  v[9]  = bf_hi(r1.x) + a2.y;
  v[10] = bf_lo(r1.y) + a2.z;  v[11] = bf_hi(r1.y) + a2.w;
  v[12] = bf_lo(r1.z) + a3.x;  v[13] = bf_hi(r1.z) + a3.y;
  v[14] = bf_lo(r1.w) + a3.z;  v[15] = bf_hi(r1.w) + a3.w;
  float h1[16];
#pragma unroll
  for (int j = 0; j < 16; j++) {
    float s = sba[j];
#pragma unroll
    for (int k = 0; k < 16; k++) s = fmaf(v[k], sWa[k * 16 + j], s);
    h1[j] = fmaxf(s, 0.f);
  }
  float o[16];
#pragma unroll
  for (int j = 0; j < 16; j++) {
    float s = sbb[j];
#pragma unroll
    for (int k = 0; k < 16; k++) s = fmaf(h1[k], sWb[k * 16 + j], s);
    o[j] = fmaxf(s, 0.f);
  }
  out[2 * n]     = make_uint4(pack_bf2(o[0], o[1]),  pack_bf2(o[2], o[3]),
                              pack_bf2(o[4], o[5]),  pack_bf2(o[6], o[7]));
  out[2 * n + 1] = make_uint4(pack_bf2(o[8], o[9]),  pack_bf2(o[10], o[11]),
                              pack_bf2(o[12], o[13]), pack_bf2(o[14], o[15]));
}

// ---------- pool: one 64-lane block per graph; batch is sorted; bf16 input ----------
__global__ __launch_bounds__(64) void pool_kernel(
    const uint4* __restrict__ h, const int* __restrict__ batch,
    float* __restrict__ g) {
  int gr = blockIdx.x;
  int lo = 0, hi = N_NODES;
  while (lo < hi) { int mid = (lo + hi) >> 1; if (batch[mid] < gr) lo = mid + 1; else hi = mid; }
  int start = lo;
  hi = N_NODES;
  while (lo < hi) { int mid = (lo + hi) >> 1; if (batch[mid] < gr + 1) lo = mid + 1; else hi = mid; }
  int end = lo;
  float acc[16];
#pragma unroll
  for (int j = 0; j < 16; j++) acc[j] = 0.f;
  for (int n = start + threadIdx.x; n < end; n += 64) {
    uint4 r0 = h[2 * n], r1 = h[2 * n + 1];
    acc[0]  += bf_lo(r0.x); acc[1]  += bf_hi(r0.x);
    acc[2]  += bf_lo(r0.y); acc[3]  += bf_hi(r0.y);
    acc[4]  += bf_lo(r0.z); acc[5]  += bf_hi(r0.z);
    acc[6]  += bf_lo(r0.w); acc[7]  += bf_hi(r0.w);
    acc[8]  += bf_lo(r1.x); acc[9]  += bf_hi(r1.x);
    acc[10] += bf_lo(r1.y); acc[11] += bf_hi(r1.y);
    acc[12] += bf_lo(r1.z); acc[13] += bf_hi(r1.z);
    acc[14] += bf_lo(r1.w); acc[15] += bf_hi(r1.w);
  }
#pragma unroll
  for (int j = 0; j < 16; j++) {
#pragma unroll
    for (int off = 32; off > 0; off >>= 1) acc[j] += __shfl_xor(acc[j], off, 64);
  }
  if (threadIdx.x == 0) {
    float4* gp = reinterpret_cast<float4*>(g + gr * 16);
#pragma unroll
    for (int q = 0; q < 4; q++)
      gp[q] = make_float4(acc[4 * q], acc[4 * q + 1], acc[4 * q + 2], acc[4 * q + 3]);
  }
}

// ---------- head: relu(g@Wl1+bl1)@Wl2+bl2 ----------
__global__ __launch_bounds__(256) void head_kernel(
    const float* __restrict__ g,
    const float* __restrict__ Wl1, const float* __restrict__ bl1,
    const float* __restrict__ Wl2, const float* __restrict__ bl2,
    float* __restrict__ out) {
  __shared__ float sW1[256], sb1[16], sW2[16];
  int t = threadIdx.x;
  if (t < 16) { sb1[t] = bl1[t]; sW2[t] = Wl2[t]; }
  for (int i = t; i < 256; i += 256) sW1[i] = Wl1[i];
  __syncthreads();
  int gr = blockIdx.x * blockDim.x + t;
  if (gr >= N_GRAPHS) return;
  float v[16];
  const float4* gp = reinterpret_cast<const float4*>(g + 16 * gr);
#pragma unroll
  for (int q = 0; q < 4; q++) {
    float4 gv = gp[q];
    v[4 * q + 0] = gv.x; v[4 * q + 1] = gv.y; v[4 * q + 2] = gv.z; v[4 * q + 3] = gv.w;
  }
  float o = bl2[0];
#pragma unroll
  for (int j = 0; j < 16; j++) {
    float s = sb1[j];
#pragma unroll
    for (int k = 0; k < 16; k++) s = fmaf(v[k], sW1[k * 16 + j], s);
    o = fmaf(fmaxf(s, 0.f), sW2[j], o);
  }
  out[gr] = o;
}

extern "C" void kernel_launch(void* const* d_in, const int* in_sizes, int n_in,
                              void* d_out, int out_size, void* d_ws, size_t ws_size,
                              hipStream_t stream) {
  const float* x     = (const float*)d_in[0];
  const int*   ei    = (const int*)d_in[1];
  const int*   src   = ei;
  const int*   dst   = ei + N_EDGES;
  const int*   batch = (const int*)d_in[2];
  const float* W1a = (const float*)d_in[3];  const float* b1a = (const float*)d_in[4];
  const float* W1b = (const float*)d_in[5];  const float* b1b = (const float*)d_in[6];
  const float* W2a = (const float*)d_in[7];  const float* b2a = (const float*)d_in[8];
  const float* W2b = (const float*)d_in[9];  const float* b2b = (const float*)d_in[10];
  const float* W3a = (const float*)d_in[11]; const float* b3a = (const float*)d_in[12];
  const float* W3b = (const float*)d_in[13]; const float* b3b = (const float*)d_in[14];
  const float* Wl1 = (const float*)d_in[15]; const float* bl1 = (const float*)d_in[16];
  const float* Wl2 = (const float*)d_in[17]; const float* bl2 = (const float*)d_in[18];
  float* out = (float*)d_out;

  // ws layout (ints). colA aliases the layer-buffer region (dead after partB).
  int*   gcurA    = (int*)d_ws;                         // NMB (pad 128)
  int*   gcur2    = gcurA + 128;                        // NMB*16=1568 (pad 2048)
  int*   rowstart = gcur2 + 2048;                       // N_NODES (pad 200192)
  int*   rowcnt   = rowstart + 200192;                  // N_NODES (pad 200192)
  float* agg2     = (float*)(rowcnt + 200192);          // N_NODES*2 (pad 400384)
  int*   col      = (int*)agg2 + 400384;                // NBUCK*CAPF = 7,202,304
  int*   U        = col + (size_t)NBUCK * CAPF;         // union region (6,623,232 ints)
  int*   colA     = U;                                  // NMB*MBCAP ints
  float* agg      = (float*)U;                          // N_NODES*16 f32 (3.2M ints)
  uint4* hA       = (uint4*)(agg + (size_t)N_NODES * 16);   // N_NODES*32B bf16
  uint4* hB       = hA + (size_t)N_NODES * 2;               // N_NODES*32B bf16
  float* g        = (float*)(hB + (size_t)N_NODES * 2);     // N_GRAPHS*16
  // U usage: 3.2M + 1.6M + 1.6M + 32K ints = 6.43M < 6.62M ✓

  const int NWAVE_BLK = N_NODES / 4;                    // 50000 (exact)
  const int N2_BLK = N_NODES / 8;                       // 25000 (exact)
  dim3 ngrid((N_NODES + 255) / 256);

  init_cursors<<<(NMB * 16 + 255) / 256, 256, 0, stream>>>(gcurA, gcur2);
  partA<<<PBLKA, 256, 0, stream>>>(src, dst, gcurA, colA);
  partB<<<NMB * PB, 256, 0, stream>>>(gcurA, colA, gcur2, col);
  sort_fine<<<NBUCK, 256, 0, stream>>>(gcur2, col, rowstart, rowcnt);

  // layer 1
  aggr2_wave<<<N2_BLK, 256, 0, stream>>>(rowstart, rowcnt, col, x, agg2);
  node_l1<<<ngrid, 256, 0, stream>>>(x, agg2, W1a, b1a, W1b, b1b, hA);
  // layer 2
  aggr16_wave<<<NWAVE_BLK, 256, 0, stream>>>(rowstart, rowcnt, col, hA, agg);
  node16<<<ngrid, 256, 0, stream>>>(hA, agg, W2a, b2a, W2b, b2b, hB);
  // layer 3
  aggr16_wave<<<NWAVE_BLK, 256, 0, stream>>>(rowstart, rowcnt, col, hB, agg);
  node16<<<ngrid, 256, 0, stream>>>(hB, agg, W3a, b3a, W3b, b3b, hA);

  pool_kernel<<<N_GRAPHS, 64, 0, stream>>>(hA, batch, g);
  head_kernel<<<(N_GRAPHS + 255) / 256, 256, 0, stream>>>(g, Wl1, bl1, Wl2, bl2, out);
}

// Round 14
// 339.907 us; speedup vs baseline: 1.0633x; 1.0633x over previous
//
#include <hip/hip_runtime.h>

#define N_NODES 200000
#define N_EDGES 6400000
#define N_GRAPHS 2000

// level-1: megabuckets of 2048 dst nodes
#define MBSHIFT 11
#define NMB 98             // ceil(200000/2048)
#define MBCAP 67584        // mean 65536 + 8 sigma
#define CHUNKA 4096        // edges per partA block
#define PBLKA 1563         // ceil(6.4M/4096)
#define CHUNKB 8192        // edges per partB chunk
#define PB 9               // partB blocks per megabucket (9*8192 >= MBCAP)

// level-2: fine buckets of 128 dst nodes
#define FSHIFT 7
#define NBUCK 1563         // ceil(200000/128)
#define CAPF 4608          // mean 4096 + 8 sigma

// ---- bf16 helpers (storage = packed u16 pairs in uint; compute = f32) ----
__device__ __forceinline__ float bf_lo(unsigned v) { return __uint_as_float(v << 16); }
__device__ __forceinline__ float bf_hi(unsigned v) { return __uint_as_float(v & 0xFFFF0000u); }
__device__ __forceinline__ unsigned pack_bf2(float lo, float hi) {
  unsigned a = __float_as_uint(lo), b = __float_as_uint(hi);
  a = (a + 0x7FFFu + ((a >> 16) & 1u)) >> 16;
  b = (b + 0x7FFFu + ((b >> 16) & 1u)) >> 16;
  return a | (b << 16);
}

__global__ __launch_bounds__(256) void init_cursors(int* __restrict__ gcurA,
                                                    int* __restrict__ gcur2) {
  int i = blockIdx.x * 256 + threadIdx.x;
  if (i < NMB) gcurA[i] = i * MBCAP;
  if (i < NMB * 16) gcur2[i] = i * CAPF;
}

// pass A: single int4 read of src/dst into registers -> LDS counting sort ->
// parallel binary-search copy-out (contiguous per-bin runs).
__global__ __launch_bounds__(256) void partA(
    const int* __restrict__ src, const int* __restrict__ dst,
    int* __restrict__ gcurA, int* __restrict__ colA) {
  __shared__ int hist[NMB], base[NMB], lcur[NMB];
  __shared__ int sc[128];
  __shared__ int sorted[CHUNKA];  // 16 KB
  int t = threadIdx.x;
  for (int i = t; i < NMB; i += 256) hist[i] = 0;
  __syncthreads();
  int e0 = blockIdx.x * CHUNKA;
  int cnt = N_EDGES - e0; if (cnt > CHUNKA) cnt = CHUNKA;  // 4096 or 2048 (mult of 1024)
  int pr[16], br[16];
#pragma unroll
  for (int k = 0; k < 4; k++) {
    if (k * 1024 < cnt) {
      int i = e0 + k * 1024 + t * 4;
      int4 d4 = *reinterpret_cast<const int4*>(dst + i);
      int4 s4 = *reinterpret_cast<const int4*>(src + i);
      br[4*k+0] = d4.x >> MBSHIFT; pr[4*k+0] = (s4.x << MBSHIFT) | (d4.x & 2047);
      br[4*k+1] = d4.y >> MBSHIFT; pr[4*k+1] = (s4.y << MBSHIFT) | (d4.y & 2047);
      br[4*k+2] = d4.z >> MBSHIFT; pr[4*k+2] = (s4.z << MBSHIFT) | (d4.z & 2047);
      br[4*k+3] = d4.w >> MBSHIFT; pr[4*k+3] = (s4.w << MBSHIFT) | (d4.w & 2047);
      atomicAdd(&hist[br[4*k+0]], 1); atomicAdd(&hist[br[4*k+1]], 1);
      atomicAdd(&hist[br[4*k+2]], 1); atomicAdd(&hist[br[4*k+3]], 1);
    } else {
      br[4*k+0] = -1; br[4*k+1] = -1; br[4*k+2] = -1; br[4*k+3] = -1;
      pr[4*k+0] = 0;  pr[4*k+1] = 0;  pr[4*k+2] = 0;  pr[4*k+3] = 0;
    }
  }
  __syncthreads();
  if (t < 128) sc[t] = (t < NMB) ? hist[t] : 0;
  __syncthreads();
  for (int off = 1; off < 128; off <<= 1) {
    int v = (t < 128 && t >= off) ? sc[t - off] : 0;
    __syncthreads();
    if (t < 128) sc[t] += v;
    __syncthreads();
  }
  if (t < NMB) {
    lcur[t] = sc[t] - hist[t];
    base[t] = hist[t] ? atomicAdd(&gcurA[t], hist[t]) : 0;
  }
  __syncthreads();
#pragma unroll
  for (int k = 0; k < 16; k++) {
    int b = br[k];
    if (b >= 0) {
      int r = atomicAdd(&lcur[b], 1);
      sorted[r] = pr[k];
    }
  }
  __syncthreads();
  // parallel copy-out: bin of element i = first b with sc[b] > i (7-step search)
  for (int i = t; i < cnt; i += 256) {
    int lo = 0, hi = NMB;
    while (lo < hi) { int mid = (lo + hi) >> 1; if (sc[mid] <= i) lo = mid + 1; else hi = mid; }
    int b = lo;
    int pos = base[b] + (i - (sc[b] - hist[b]));
    if (pos < (b + 1) * MBCAP) colA[pos] = sorted[i];  // 8-sigma guard
  }
}

// pass B: single int4 read into 32 regs/thread -> direct global scatter into the
// block's reserved (contiguous, block-private) per-fine-bucket ranges.
__global__ __launch_bounds__(256) void partB(
    const int* __restrict__ gcurA, const int* __restrict__ colA,
    int* __restrict__ gcur2, int* __restrict__ col) {
  __shared__ int hist[16], base[16], lcur[16];
  int t = threadIdx.x;
  int mb = blockIdx.x / PB, j = blockIdx.x % PB;
  int mbbase = mb * MBCAP;
  int mbcnt = gcurA[mb] - mbbase; if (mbcnt > MBCAP) mbcnt = MBCAP;
  int c0 = j * CHUNKB;
  int cnt = mbcnt - c0;
  if (cnt > CHUNKB) cnt = CHUNKB;
  if (cnt < 0) cnt = 0;
  if (t < 16) { hist[t] = 0; }
  __syncthreads();
  const int* seg = colA + mbbase + c0;
  int pr[32];
#pragma unroll
  for (int k = 0; k < 8; k++) {
    int i = k * 1024 + t * 4;
    if (i + 3 < cnt) {
      int4 v = *reinterpret_cast<const int4*>(seg + i);
      pr[4*k+0] = v.x; pr[4*k+1] = v.y; pr[4*k+2] = v.z; pr[4*k+3] = v.w;
      atomicAdd(&hist[(v.x & 2047) >> FSHIFT], 1);
      atomicAdd(&hist[(v.y & 2047) >> FSHIFT], 1);
      atomicAdd(&hist[(v.z & 2047) >> FSHIFT], 1);
      atomicAdd(&hist[(v.w & 2047) >> FSHIFT], 1);
    } else {
#pragma unroll
      for (int q = 0; q < 4; q++) {
        int i2 = i + q;
        if (i2 < cnt) {
          int p = seg[i2];
          pr[4*k+q] = p;
          atomicAdd(&hist[(p & 2047) >> FSHIFT], 1);
        } else pr[4*k+q] = -1;
      }
    }
  }
  __syncthreads();
  if (t < 16) {
    base[t] = hist[t] ? atomicAdd(&gcur2[mb * 16 + t], hist[t]) : 0;
    lcur[t] = 0;
  }
  __syncthreads();
#pragma unroll
  for (int k = 0; k < 32; k++) {
    int p = pr[k];
    if (p >= 0) {
      int b = (p & 2047) >> FSHIFT;
      int r = atomicAdd(&lcur[b], 1);
      int pos = base[b] + r;
      if (pos < (mb * 16 + b + 1) * CAPF)                  // 8-sigma guard
        col[pos] = ((p >> MBSHIFT) << FSHIFT) | (p & 127); // src<<7 | dst&127
    }
  }
}

// fine sort: single read into 18 regs/thread -> 128-bin LDS sort -> linear write-back
__global__ __launch_bounds__(256) void sort_fine(
    const int* __restrict__ gcur2, int* __restrict__ col,
    int* __restrict__ rowstart, int* __restrict__ rowcnt) {
  __shared__ int hist[128], sc[128], lcur[128];
  __shared__ int sorted[CAPF];   // 18 KB
  int t = threadIdx.x;
  int fb = blockIdx.x;
  int beg = fb * CAPF;
  int cnt = gcur2[fb] - beg; if (cnt > CAPF) cnt = CAPF;
  if (t < 128) hist[t] = 0;
  __syncthreads();
  int pr[18];
#pragma unroll
  for (int k = 0; k < 18; k++) {
    int i = k * 256 + t;
    int p = (i < cnt) ? col[beg + i] : -1;
    pr[k] = p;
    if (p >= 0) atomicAdd(&hist[p & 127], 1);
  }
  __syncthreads();
  if (t < 128) sc[t] = hist[t];
  __syncthreads();
  for (int off = 1; off < 128; off <<= 1) {
    int v = (t < 128 && t >= off) ? sc[t - off] : 0;
    __syncthreads();
    if (t < 128) sc[t] += v;
    __syncthreads();
  }
  if (t < 128) {
    int excl = sc[t] - hist[t];
    lcur[t] = excl;
    int n = fb * 128 + t;
    if (n < N_NODES) { rowstart[n] = beg + excl; rowcnt[n] = hist[t]; }
  }
  __syncthreads();
#pragma unroll
  for (int k = 0; k < 18; k++) {
    int p = pr[k];
    if (p >= 0) {
      int r = atomicAdd(&lcur[p & 127], 1);
      sorted[r] = p >> FSHIFT;   // src only, grouped by dst
    }
  }
  __syncthreads();
  for (int i = t; i < cnt; i += 256) col[beg + i] = sorted[i];
}

// ---------- layer 1 aggregation: 32 lanes per node (2 nodes/wave), dim 2 ----------
__global__ __launch_bounds__(256) void aggr2_wave(
    const int* __restrict__ rowstart, const int* __restrict__ rowcnt,
    const int* __restrict__ col, const float* __restrict__ x,
    float* __restrict__ agg2) {
  int n = blockIdx.x * 8 + (threadIdx.x >> 5);  // 200000 = 25000*8 exactly
  int l32 = threadIdx.x & 31;
  int e0 = rowstart[n], c = rowcnt[n];
  float a0 = 0.f, a1 = 0.f;
  for (int idx = l32; idx < c; idx += 32) {
    int s = col[e0 + idx];
    float2 u = *reinterpret_cast<const float2*>(x + 2 * s);
    a0 += u.x; a1 += u.y;
  }
#pragma unroll
  for (int off = 1; off <= 16; off <<= 1) {  // stays within each 32-lane group
    a0 += __shfl_xor(a0, off, 64);
    a1 += __shfl_xor(a1, off, 64);
  }
  if (l32 == 0) {
    *reinterpret_cast<float2*>(agg2 + 2 * n) = make_float2(a0, a1);
  }
}

// ---------- layers 2/3 aggregation: one wave per node, dim 16, bf16 gather ----------
__global__ __launch_bounds__(256) void aggr16_wave(
    const int* __restrict__ rowstart, const int* __restrict__ rowcnt,
    const int* __restrict__ col, const uint4* __restrict__ hbf,
    float* __restrict__ agg) {
  int n = blockIdx.x * 4 + (threadIdx.x >> 6);
  int lane = threadIdx.x & 63;
  int e0 = rowstart[n], c = rowcnt[n];
  float a[8];
#pragma unroll
  for (int j = 0; j < 8; j++) a[j] = 0.f;
  int half = lane & 1;
  for (int idx = (lane >> 1); idx < c; idx += 32) {
    int s = col[e0 + idx];
    uint4 u = hbf[2 * s + half];   // 8 bf16 = 16 B; pair covers the 32B row (one 64B line)
    a[0] += bf_lo(u.x); a[1] += bf_hi(u.x);
    a[2] += bf_lo(u.y); a[3] += bf_hi(u.y);
    a[4] += bf_lo(u.z); a[5] += bf_hi(u.z);
    a[6] += bf_lo(u.w); a[7] += bf_hi(u.w);
  }
#pragma unroll
  for (int off = 2; off <= 32; off <<= 1) {
#pragma unroll
    for (int j = 0; j < 8; j++) a[j] += __shfl_xor(a[j], off, 64);
  }
  if (lane < 2) {
    float* dstp = agg + (size_t)n * 16 + 8 * lane;
    *reinterpret_cast<float4*>(dstp)     = make_float4(a[0], a[1], a[2], a[3]);
    *reinterpret_cast<float4*>(dstp + 4) = make_float4(a[4], a[5], a[6], a[7]);
  }
}

// ---------- layer 1 node MLP (2 -> 16 -> 16), outer relu, bf16 out ----------
__global__ __launch_bounds__(256) void node_l1(
    const float* __restrict__ x, const float* __restrict__ agg2,
    const float* __restrict__ Wa, const float* __restrict__ ba,
    const float* __restrict__ Wb, const float* __restrict__ bb,
    uint4* __restrict__ out) {
  __shared__ float sWa[32], sba[16], sWb[256], sbb[16];
  int t = threadIdx.x;
  if (t < 32) sWa[t] = Wa[t];
  if (t < 16) { sba[t] = ba[t]; sbb[t] = bb[t]; }
  for (int i = t; i < 256; i += 256) sWb[i] = Wb[i];
  __syncthreads();
  int n = blockIdx.x * blockDim.x + t;
  if (n >= N_NODES) return;
  float2 xv = *reinterpret_cast<const float2*>(x + 2 * n);
  float2 av = *reinterpret_cast<const float2*>(agg2 + 2 * n);
  float v0 = xv.x + av.x, v1 = xv.y + av.y;
  float h1[16];
#pragma unroll
  for (int j = 0; j < 16; j++)
    h1[j] = fmaxf(fmaf(v0, sWa[j], fmaf(v1, sWa[16 + j], sba[j])), 0.f);
  float o[16];
#pragma unroll
  for (int j = 0; j < 16; j++) {
    float s = sbb[j];
#pragma unroll
    for (int k = 0; k < 16; k++) s = fmaf(h1[k], sWb[k * 16 + j], s);
    o[j] = fmaxf(s, 0.f);
  }
  out[2 * n]     = make_uint4(pack_bf2(o[0], o[1]),  pack_bf2(o[2], o[3]),
                              pack_bf2(o[4], o[5]),  pack_bf2(o[6], o[7]));
  out[2 * n + 1] = make_uint4(pack_bf2(o[8], o[9]),  pack_bf2(o[10], o[11]),
                              pack_bf2(o[12], o[13]), pack_bf2(o[14], o[15]));
}

// ---------- layers 2/3 node MLP (16 -> 16 -> 16), outer relu, bf16 in/out ----------
__global__ __launch_bounds__(256) void node16(
    const uint4* __restrict__ hin, const float* __restrict__ aggr,
    const float* __restrict__ Wa, const float* __restrict__ ba,
    const float* __restrict__ Wb, const float* __restrict__ bb,
    uint4* __restrict__ out) {
  __shared__ float sWa[256], sba[16], sWb[256], sbb[16];
  int t = threadIdx.x;
  if (t < 16) { sba[t] = ba[t]; sbb[t] = bb[t]; }
  for (int i = t; i < 256; i += 256) { sWa[i] = Wa[i]; sWb[i] = Wb[i]; }
  __syncthreads();
  int n = blockIdx.x * blockDim.x + t;
  if (n >= N_NODES) return;
  uint4 r0 = hin[2 * n], r1 = hin[2 * n + 1];
  const float4* ap = reinterpret_cast<const float4*>(aggr + 16 * n);
  float4 a0 = ap[0], a1 = ap[1], a2 = ap[2], a3 = ap[3];
  float v[16];
  v[0]  = bf_lo(r0.x) + a0.x;  v[1]  = bf_hi(r0.x) + a0.y;
  v[2]  = bf_lo(r0.y) + a0.z;  v[3]  = bf_hi(r0.y) + a0.w;
  v[4]  = bf_lo(r0.z) + a1.x;  v[5]  = bf_hi(r0.z) + a1.y;
  v[6]  = bf_lo(r0.w) + a1.z;  v[7]  = bf_hi(r0.w) + a1.w;
  v[8]  = bf_lo(r1.x) + a2.x;  v[9]  = bf_hi(r1.x) + a2.y;
  v[10] = bf_lo(r1.y) + a2.z;  v[11] = bf_hi(r1.y) + a2.w;
  v[12] = bf_lo(r1.z) + a3.x;  v[13] = bf_hi(r1.z) + a3.y;
  v[14] = bf_lo(r1.w) + a3.z;  v[15] = bf_hi(r1.w) + a3.w;
  float h1[16];
#pragma unroll
  for (int j = 0; j < 16; j++) {
    float s = sba[j];
#pragma unroll
    for (int k = 0; k < 16; k++) s = fmaf(v[k], sWa[k * 16 + j], s);
    h1[j] = fmaxf(s, 0.f);
  }
  float o[16];
#pragma unroll
  for (int j = 0; j < 16; j++) {
    float s = sbb[j];
#pragma unroll
    for (int k = 0; k < 16; k++) s = fmaf(h1[k], sWb[k * 16 + j], s);
    o[j] = fmaxf(s, 0.f);
  }
  out[2 * n]     = make_uint4(pack_bf2(o[0], o[1]),  pack_bf2(o[2], o[3]),
                              pack_bf2(o[4], o[5]),  pack_bf2(o[6], o[7]));
  out[2 * n + 1] = make_uint4(pack_bf2(o[8], o[9]),  pack_bf2(o[10], o[11]),
                              pack_bf2(o[12], o[13]), pack_bf2(o[14], o[15]));
}

// ---------- pool: one 64-lane block per graph; batch is sorted; bf16 input ----------
__global__ __launch_bounds__(64) void pool_kernel(
    const uint4* __restrict__ h, const int* __restrict__ batch,
    float* __restrict__ g) {
  int gr = blockIdx.x;
  int lo = 0, hi = N_NODES;
  while (lo < hi) { int mid = (lo + hi) >> 1; if (batch[mid] < gr) lo = mid + 1; else hi = mid; }
  int start = lo;
  hi = N_NODES;
  while (lo < hi) { int mid = (lo + hi) >> 1; if (batch[mid] < gr + 1) lo = mid + 1; else hi = mid; }
  int end = lo;
  float acc[16];
#pragma unroll
  for (int j = 0; j < 16; j++) acc[j] = 0.f;
  for (int n = start + threadIdx.x; n < end; n += 64) {
    uint4 r0 = h[2 * n], r1 = h[2 * n + 1];
    acc[0]  += bf_lo(r0.x); acc[1]  += bf_hi(r0.x);
    acc[2]  += bf_lo(r0.y); acc[3]  += bf_hi(r0.y);
    acc[4]  += bf_lo(r0.z); acc[5]  += bf_hi(r0.z);
    acc[6]  += bf_lo(r0.w); acc[7]  += bf_hi(r0.w);
    acc[8]  += bf_lo(r1.x); acc[9]  += bf_hi(r1.x);
    acc[10] += bf_lo(r1.y); acc[11] += bf_hi(r1.y);
    acc[12] += bf_lo(r1.z); acc[13] += bf_hi(r1.z);
    acc[14] += bf_lo(r1.w); acc[15] += bf_hi(r1.w);
  }
#pragma unroll
  for (int j = 0; j < 16; j++) {
#pragma unroll
    for (int off = 32; off > 0; off >>= 1) acc[j] += __shfl_xor(acc[j], off, 64);
  }
  if (threadIdx.x == 0) {
    float4* gp = reinterpret_cast<float4*>(g + gr * 16);
#pragma unroll
    for (int q = 0; q < 4; q++)
      gp[q] = make_float4(acc[4 * q], acc[4 * q + 1], acc[4 * q + 2], acc[4 * q + 3]);
  }
}

// ---------- head: relu(g@Wl1+bl1)@Wl2+bl2 ----------
__global__ __launch_bounds__(256) void head_kernel(
    const float* __restrict__ g,
    const float* __restrict__ Wl1, const float* __restrict__ bl1,
    const float* __restrict__ Wl2, const float* __restrict__ bl2,
    float* __restrict__ out) {
  __shared__ float sW1[256], sb1[16], sW2[16];
  int t = threadIdx.x;
  if (t < 16) { sb1[t] = bl1[t]; sW2[t] = Wl2[t]; }
  for (int i = t; i < 256; i += 256) sW1[i] = Wl1[i];
  __syncthreads();
  int gr = blockIdx.x * blockDim.x + t;
  if (gr >= N_GRAPHS) return;
  float v[16];
  const float4* gp = reinterpret_cast<const float4*>(g + 16 * gr);
#pragma unroll
  for (int q = 0; q < 4; q++) {
    float4 gv = gp[q];
    v[4 * q + 0] = gv.x; v[4 * q + 1] = gv.y; v[4 * q + 2] = gv.z; v[4 * q + 3] = gv.w;
  }
  float o = bl2[0];
#pragma unroll
  for (int j = 0; j < 16; j++) {
    float s = sb1[j];
#pragma unroll
    for (int k = 0; k < 16; k++) s = fmaf(v[k], sW1[k * 16 + j], s);
    o = fmaf(fmaxf(s, 0.f), sW2[j], o);
  }
  out[gr] = o;
}

extern "C" void kernel_launch(void* const* d_in, const int* in_sizes, int n_in,
                              void* d_out, int out_size, void* d_ws, size_t ws_size,
                              hipStream_t stream) {
  const float* x     = (const float*)d_in[0];
  const int*   ei    = (const int*)d_in[1];
  const int*   src   = ei;
  const int*   dst   = ei + N_EDGES;
  const int*   batch = (const int*)d_in[2];
  const float* W1a = (const float*)d_in[3];  const float* b1a = (const float*)d_in[4];
  const float* W1b = (const float*)d_in[5];  const float* b1b = (const float*)d_in[6];
  const float* W2a = (const float*)d_in[7];  const float* b2a = (const float*)d_in[8];
  const float* W2b = (const float*)d_in[9];  const float* b2b = (const float*)d_in[10];
  const float* W3a = (const float*)d_in[11]; const float* b3a = (const float*)d_in[12];
  const float* W3b = (const float*)d_in[13]; const float* b3b = (const float*)d_in[14];
  const float* Wl1 = (const float*)d_in[15]; const float* bl1 = (const float*)d_in[16];
  const float* Wl2 = (const float*)d_in[17]; const float* bl2 = (const float*)d_in[18];
  float* out = (float*)d_out;

  // ws layout (ints). colA aliases the layer-buffer region (dead after partB).
  int*   gcurA    = (int*)d_ws;                         // NMB (pad 128)
  int*   gcur2    = gcurA + 128;                        // NMB*16=1568 (pad 2048)
  int*   rowstart = gcur2 + 2048;                       // N_NODES (pad 200192)
  int*   rowcnt   = rowstart + 200192;                  // N_NODES (pad 200192)
  float* agg2     = (float*)(rowcnt + 200192);          // N_NODES*2 (pad 400384)
  int*   col      = (int*)agg2 + 400384;                // NBUCK*CAPF = 7,202,304
  int*   U        = col + (size_t)NBUCK * CAPF;         // union region (6,623,232 ints)
  int*   colA     = U;                                  // NMB*MBCAP ints
  float* agg      = (float*)U;                          // N_NODES*16 f32 (3.2M ints)
  uint4* hA       = (uint4*)(agg + (size_t)N_NODES * 16);   // N_NODES*32B bf16
  uint4* hB       = hA + (size_t)N_NODES * 2;               // N_NODES*32B bf16
  float* g        = (float*)(hB + (size_t)N_NODES * 2);     // N_GRAPHS*16
  // U usage: 3.2M + 1.6M + 1.6M + 32K ints = 6.43M < 6.62M ✓

  const int NWAVE_BLK = N_NODES / 4;                    // 50000 (exact)
  const int N2_BLK = N_NODES / 8;                       // 25000 (exact)
  dim3 ngrid((N_NODES + 255) / 256);

  init_cursors<<<(NMB * 16 + 255) / 256, 256, 0, stream>>>(gcurA, gcur2);
  partA<<<PBLKA, 256, 0, stream>>>(src, dst, gcurA, colA);
  partB<<<NMB * PB, 256, 0, stream>>>(gcurA, colA, gcur2, col);
  sort_fine<<<NBUCK, 256, 0, stream>>>(gcur2, col, rowstart, rowcnt);

  // layer 1
  aggr2_wave<<<N2_BLK, 256, 0, stream>>>(rowstart, rowcnt, col, x, agg2);
  node_l1<<<ngrid, 256, 0, stream>>>(x, agg2, W1a, b1a, W1b, b1b, hA);
  // layer 2
  aggr16_wave<<<NWAVE_BLK, 256, 0, stream>>>(rowstart, rowcnt, col, hA, agg);
  node16<<<ngrid, 256, 0, stream>>>(hA, agg, W2a, b2a, W2b, b2b, hB);
  // layer 3
  aggr16_wave<<<NWAVE_BLK, 256, 0, stream>>>(rowstart, rowcnt, col, hB, agg);
  node16<<<ngrid, 256, 0, stream>>>(hB, agg, W3a, b3a, W3b, b3b, hA);

  pool_kernel<<<N_GRAPHS, 64, 0, stream>>>(hA, batch, g);
  head_kernel<<<(N_GRAPHS + 255) / 256, 256, 0, stream>>>(g, Wl1, bl1, Wl2, bl2, out);
}